// Round 5
// baseline (449.388 us; speedup 1.0000x reference)
//
#include <hip/hip_runtime.h>
#include <math.h>

#define HH 128
#define WW 128
#define CG 8
#define NN 256
#define HWSZ (HH*WW)
#define GB (36*36*8)   // gated-tile base offset (ushort units)

typedef __bf16 bf16x8 __attribute__((ext_vector_type(8)));
typedef short short8v __attribute__((ext_vector_type(8)));
typedef float f32x4 __attribute__((ext_vector_type(4)));

__device__ __forceinline__ float sigmoidf_(float x){ return 1.0f/(1.0f+__expf(-x)); }

__device__ __forceinline__ unsigned short f2bf(float x){
  __bf16 h = (__bf16)x;
  return __builtin_bit_cast(unsigned short, h);
}
__device__ __forceinline__ float bf2f(unsigned short h){
  union { unsigned u; float f; } v; v.u = ((unsigned)h) << 16; return v.f;
}

// x1-path weight (w5*sw2 + folded sw1*w3, tap25 = sw0*w1 — Agn folded into tile)
__device__ __forceinline__ float wx1_(const float* w1, const float* w3, const float* w5,
                                      float sw0, float sw1, float sw2,
                                      int oc, int ic, int tap){
  if (tap < 25){
    int ky = tap/5, kx = tap - ky*5;
    float wv = sw2 * w5[oc*200 + ic*25 + tap];
    if (ky >= 1 && ky <= 3 && kx >= 1 && kx <= 3)
      wv = fmaf(sw1, w3[oc*72 + ic*9 + (ky-1)*3 + (kx-1)], wv);
    return wv;
  }
  if (tap == 25) return sw0 * w1[oc*CG + ic];
  return 0.f;
}
__device__ __forceinline__ float wx2_(const float* w3, int oc, int ic, int tap){
  if (tap < 25){
    int ky = tap/5, kx = tap - ky*5;
    if (ky >= 1 && ky <= 3 && kx >= 1 && kx <= 3)
      return w3[oc*72 + ic*9 + (ky-1)*3 + (kx-1)];
  }
  return 0.f;
}

// ---------------- Kernel WB: precompute n-independent B tensors + zero gacc ----
__global__ void kWB(const float* __restrict__ w1, const float* __restrict__ w3,
                    const float* __restrict__ w5, const float* __restrict__ scw,
                    const float* __restrict__ spw,
                    unsigned short* __restrict__ BH, unsigned short* __restrict__ BL,
                    float* __restrict__ gacc){
  if (blockIdx.x == 23){
    for (int i = threadIdx.x; i < NN*32; i += 256) gacc[i] = 0.f;
    return;
  }
  int e = blockIdx.x*256 + threadIdx.x;
  float a = scw[0], b = scw[1], c = scw[2];
  float m = fmaxf(a, fmaxf(b, c));
  float e0 = __expf(a-m), e1 = __expf(b-m), e2 = __expf(c-m);
  float inv = 1.0f/(e0+e1+e2);
  float sw0 = e0*inv, sw1 = e1*inv, sw2 = e2*inv;
  if (e < 3584){
    int s = e >> 9, rem = e & 511, nn = rem >> 5, kk = rem & 31;
    int tap = s*4 + (kk >> 3), ic = kk & 7;
    float wv = (nn < 8) ? wx1_(w1,w3,w5,sw0,sw1,sw2,nn,ic,tap)
                        : wx2_(w3,nn-8,ic,tap);
    BH[e] = f2bf(wv);
  } else if (e < 5824){
    int e2 = e - 3584;
    int s = e2 / 320, rem = e2 - s*320, nn = rem >> 5, kk = rem & 31;
    int tap = s*4 + (kk >> 3), ic = kk & 7;
    float outv;
    if (nn < 8){
      float wv = wx1_(w1,w3,w5,sw0,sw1,sw2,nn,ic,tap);
      outv = wv - bf2f(f2bf(wv));
    } else {
      float sum = 0.f;
      #pragma unroll
      for (int oc = 0; oc < CG; ++oc){
        float wv = (nn == 8) ? wx1_(w1,w3,w5,sw0,sw1,sw2,oc,ic,tap)
                             : wx2_(w3,oc,ic,tap);
        sum = fmaf(spw[oc], wv, sum);
      }
      outv = sum;
    }
    BL[e2] = f2bf(outv);
  }
}

// ---------------- Kernel A1: per-(n,c) row & column means ----------------------
__global__ __launch_bounds__(256) void kA1(const float* __restrict__ gx,
                                           float* __restrict__ xh_ws,
                                           float* __restrict__ xw_ws){
  int b = blockIdx.x; int n = b >> 3; int c = b & 7;
  int tid = threadIdx.x;
  __shared__ float colpart[2][WW];
  const float* img = gx + (size_t)(n*CG+c)*HWSZ;
  int w = tid & 127, half = tid >> 7;
  float acc = 0.f;
  const float* p = img + half*64*WW + w;
  for (int h = 0; h < 64; ++h) acc += p[h*WW];
  colpart[half][w] = acc;
  int h2 = tid >> 1, wh = tid & 1;
  float racc = 0.f;
  const float* rp = img + h2*WW + wh*64;
  for (int j = 0; j < 64; ++j) racc += rp[j];
  racc += __shfl_xor(racc, 1);
  __syncthreads();
  if (tid < WW) xw_ws[(n*CG+c)*WW + tid] = (colpart[0][tid] + colpart[1][tid]) * (1.0f/HH);
  if (wh == 0) xh_ws[(n*CG+c)*HH + h2] = racc * (1.0f/WW);
}

// ---------------- Kernel A2: 8x8 fuse conv + sigmoid ---------------------------
__global__ __launch_bounds__(256) void kA2(const float* __restrict__ xh_ws,
                                           const float* __restrict__ xw_ws,
                                           const float* __restrict__ afw,
                                           float* __restrict__ sig_h,
                                           float* __restrict__ sig_w){
  int n = blockIdx.x;
  int tid = threadIdx.x;
  if (tid < HH){
    int h = tid;
    float v[CG];
    #pragma unroll
    for (int c = 0; c < CG; ++c) v[c] = xh_ws[(n*CG+c)*HH + h];
    #pragma unroll
    for (int o = 0; o < CG; ++o){
      float s = 0.f;
      #pragma unroll
      for (int i = 0; i < CG; ++i) s = fmaf(afw[o*CG+i], v[i], s);
      sig_h[(n*CG+o)*HH + h] = sigmoidf_(s);
    }
  } else {
    int w = tid - 128;
    float v[CG];
    #pragma unroll
    for (int c = 0; c < CG; ++c) v[c] = xw_ws[(n*CG+c)*WW + w];
    #pragma unroll
    for (int o = 0; o < CG; ++o){
      float s = 0.f;
      #pragma unroll
      for (int i = 0; i < CG; ++i) s = fmaf(afw[o*CG+i], v[i], s);
      sig_w[(n*CG+o)*WW + w] = sigmoidf_(s);
    }
  }
}

// ---------------- Kernel B: GroupNorm stats + interleaved bf16 copy of x -------
// Block per n. float4 reads of all 8 channels; writes xbf[n][px][ic8] (ushort8,
// coalesced), GN affine coefs Bgn, and sighA = sigh*Agn.
__global__ __launch_bounds__(256) void kB(const float* __restrict__ gx,
                                          const float* __restrict__ sig_h,
                                          const float* __restrict__ sig_w,
                                          const float* __restrict__ gn_w,
                                          const float* __restrict__ gn_b,
                                          float* __restrict__ Bgn,
                                          float* __restrict__ sighA,
                                          unsigned short* __restrict__ xbf){
  int n = blockIdx.x;
  int tid = threadIdx.x;
  __shared__ float sh[CG][HH];
  __shared__ float swv[CG][WW];
  __shared__ float red[2][CG][4];
  __shared__ float sA[CG];
  for (int i = tid; i < CG*HH; i += 256) sh[i>>7][i&127] = sig_h[n*CG*HH + i];
  for (int i = tid; i < CG*WW; i += 256) swv[i>>7][i&127] = sig_w[n*CG*WW + i];
  __syncthreads();
  const float* base = gx + (size_t)n*CG*HWSZ;
  unsigned short* xb = xbf + (size_t)n*HWSZ*8;
  float s1[CG], s2[CG];
  #pragma unroll
  for (int c = 0; c < CG; ++c){ s1[c] = 0.f; s2[c] = 0.f; }
  for (int it = 0; it < 16; ++it){
    int px = (it*256 + tid)*4;
    int h = px >> 7, w = px & 127;
    float4 v[CG];
    #pragma unroll
    for (int c = 0; c < CG; ++c)
      v[c] = *reinterpret_cast<const float4*>(base + (size_t)c*HWSZ + px);
    #pragma unroll
    for (int c = 0; c < CG; ++c){
      float shc = sh[c][h];
      const float* vc = (const float*)&v[c];
      #pragma unroll
      for (int j = 0; j < 4; ++j){
        float t = vc[j] * shc * swv[c][w+j];
        s1[c] += t; s2[c] = fmaf(t, t, s2[c]);
      }
    }
    #pragma unroll
    for (int j = 0; j < 4; ++j){
      uint4 pk; unsigned* pw = (unsigned*)&pk;
      #pragma unroll
      for (int p = 0; p < 4; ++p){
        float a0 = ((const float*)&v[2*p])[j];
        float a1 = ((const float*)&v[2*p+1])[j];
        pw[p] = (unsigned)f2bf(a0) | ((unsigned)f2bf(a1) << 16);
      }
      *reinterpret_cast<uint4*>(xb + (size_t)(px + j)*8) = pk;
    }
  }
  int wv = tid >> 6, ln = tid & 63;
  #pragma unroll
  for (int c = 0; c < CG; ++c){
    #pragma unroll
    for (int off = 32; off; off >>= 1){
      s1[c] += __shfl_down(s1[c], off);
      s2[c] += __shfl_down(s2[c], off);
    }
  }
  if (ln == 0){
    #pragma unroll
    for (int c = 0; c < CG; ++c){ red[0][c][wv] = s1[c]; red[1][c][wv] = s2[c]; }
  }
  __syncthreads();
  if (tid < CG){
    int c = tid;
    float S1 = red[0][c][0]+red[0][c][1]+red[0][c][2]+red[0][c][3];
    float S2 = red[1][c][0]+red[1][c][1]+red[1][c][2]+red[1][c][3];
    float mu  = S1 * (1.0f/HWSZ);
    float var = S2 * (1.0f/HWSZ) - mu*mu;
    float rstd = rsqrtf(var + 1e-5f);
    float A = rstd * gn_w[c];
    Bgn[n*CG+c] = gn_b[c] - mu*A;
    sA[c] = A;
  }
  __syncthreads();
  for (int i = tid; i < CG*HH; i += 256)
    sighA[n*CG*HH + i] = sh[i>>7][i&127] * sA[i>>7];
}

// ---------------- Kernel C: MFMA implicit-GEMM fused convs ---------------------
// Stages from interleaved bf16 xbf: one ushort8 per halo pixel (no conversion);
// gated 32x32 center tile built from the same packed data (shift-unpack + mul).
// B tensors precomputed (kWB); pair-processing reuses B fragments across 2 MFMAs.
__global__ __launch_bounds__(256) void kC(const unsigned short* __restrict__ xbf,
                                          const float* __restrict__ w1,
                                          const float* __restrict__ scale_w,
                                          const float* __restrict__ spw,
                                          const float* __restrict__ sig_w,
                                          const float* __restrict__ sighA,
                                          const float* __restrict__ Bgn,
                                          const unsigned short* __restrict__ BHg,
                                          const unsigned short* __restrict__ BLog,
                                          unsigned short* __restrict__ x1m,
                                          unsigned short* __restrict__ x2m,
                                          float* __restrict__ gacc){
  __shared__ __align__(16) unsigned short tile[36*36*8 + 32*32*8]; // 37120 B
  __shared__ float shf[CG*32];     // sigh*Agn, f32
  __shared__ float swf[CG*32];     // sigw, f32
  __shared__ float constA[CG];

  int tid = threadIdx.x;
  int bb = blockIdx.x;
  int n  = bb >> 4;
  int t_ = bb & 15;
  int y0 = (t_ >> 2) * 32;
  int x0 = (t_ & 3) * 32;

  int lane = tid & 63, wid = tid >> 6;
  int pr = lane & 15, tg = lane >> 4;

  // B fragments from global (coalesced, L2-resident)
  bf16x8 bH[7], bL[7];
  #pragma unroll
  for (int s = 0; s < 7; ++s)
    bH[s] = *reinterpret_cast<const bf16x8*>(BHg + s*512 + pr*32 + tg*8);
  short8v zs = {0,0,0,0,0,0,0,0};
  bf16x8 zb = __builtin_bit_cast(bf16x8, zs);
  if (pr < 10){
    #pragma unroll
    for (int s = 0; s < 7; ++s)
      bL[s] = *reinterpret_cast<const bf16x8*>(BLog + s*320 + pr*32 + tg*8);
  } else {
    #pragma unroll
    for (int s = 0; s < 7; ++s) bL[s] = zb;
  }

  float sw0;
  {
    float a = scale_w[0], b = scale_w[1], c = scale_w[2];
    float m = fmaxf(a, fmaxf(b, c));
    float e0 = __expf(a-m), e1 = __expf(b-m), e2 = __expf(c-m);
    sw0 = e0 / (e0+e1+e2);
  }
  {
    int ic = tid >> 5, k = tid & 31;
    shf[ic*32+k] = sighA[(n*CG+ic)*HH + y0 + k];
    swf[ic*32+k] = sig_w[(n*CG+ic)*WW + x0 + k];
  }
  if (tid < CG){
    float s = 0.f;
    #pragma unroll
    for (int i = 0; i < CG; ++i) s = fmaf(w1[tid*CG+i], Bgn[n*CG+i], s);
    constA[tid] = sw0 * s;
  }
  __syncthreads();

  // fused staging from xbf: raw 36x36 halo + gated 32x32 center
  const unsigned short* xb = xbf + (size_t)n*HWSZ*8;
  for (int e = tid; e < 1296; e += 256){
    int yy = e / 36, xx = e - yy*36;
    int gy = y0 + yy - 2, gz = x0 + xx - 2;
    uint4 pk;
    if ((unsigned)gy < HH && (unsigned)gz < WW)
      pk = *reinterpret_cast<const uint4*>(xb + (size_t)(gy*WW + gz)*8);
    else
      pk = make_uint4(0u, 0u, 0u, 0u);
    *reinterpret_cast<uint4*>(&tile[e*8]) = pk;
    int yl = yy - 2, xl = xx - 2;
    if ((unsigned)yl < 32u && (unsigned)xl < 32u){
      unsigned* pw = (unsigned*)&pk;
      uint4 gk; unsigned* gw = (unsigned*)&gk;
      #pragma unroll
      for (int p = 0; p < 4; ++p){
        float lo = __builtin_bit_cast(float, pw[p] << 16);
        float hi = __builtin_bit_cast(float, pw[p] & 0xffff0000u);
        float t0 = lo * shf[(2*p)*32   + yl] * swf[(2*p)*32   + xl];
        float t1 = hi * shf[(2*p+1)*32 + yl] * swf[(2*p+1)*32 + xl];
        gw[p] = (unsigned)f2bf(t0) | ((unsigned)f2bf(t1) << 16);
      }
      *reinterpret_cast<uint4*>(&tile[GB + (yl*32 + xl)*8]) = gk;
    }
  }

  // per-lane tap geometry (raw: stride 36 rows; gated: stride 32 rows at GB)
  int strd[7], ofs[7];
  #pragma unroll
  for (int s = 0; s < 7; ++s){
    int t = s*4 + tg;
    if (t < 25){ int ky = t/5, kx = t - ky*5; strd[s] = 36*8; ofs[s] = (ky*36 + kx)*8; }
    else if (t == 25){ strd[s] = 32*8; ofs[s] = GB; }
    else { strd[s] = 36*8; ofs[s] = 0; }   // dummy taps (B=0)
  }
  float Cd1 = 0.f;
  #pragma unroll
  for (int oc = 0; oc < CG; ++oc) Cd1 = fmaf(spw[oc], constA[oc], Cd1);
  float cA = (pr < 8) ? constA[pr] : 0.f;
  int gsrc = (lane & 48) | (pr < 8 ? 8 : 9);
  __syncthreads();

  float sAcc = 0.f, qAcc = 0.f;

#define EPI(P, Q, GXX) do { \
    float gq[4]; \
    _Pragma("unroll") \
    for (int r = 0; r < 4; ++r) gq[r] = __shfl(Q[r], gsrc); \
    ushort4 u; \
    _Pragma("unroll") \
    for (int r = 0; r < 4; ++r){ \
      float vvr = (pr < 8) ? (P[r] + Q[r] + cA) : P[r]; \
      float d   = (pr < 8) ? (gq[r] + Cd1) : gq[r]; \
      float sg  = sigmoidf_(d); \
      sAcc += vvr; \
      qAcc = fmaf(vvr, sg, qAcc); \
      ((unsigned short*)&u)[r] = f2bf(vvr); \
    } \
    size_t off = ((size_t)(n*CG + (pr & 7))*HH + (y0 + yl))*WW + (GXX); \
    if (pr < 8) *reinterpret_cast<ushort4*>(x1m + off) = u; \
    else        *reinterpret_cast<ushort4*>(x2m + off) = u; \
  } while(0)

  #pragma unroll 1
  for (int ii = 0; ii < 8; ++ii){
    int yl = wid*8 + ii;
    f32x4 P0 = {0.f,0.f,0.f,0.f}, Q0 = {0.f,0.f,0.f,0.f};
    f32x4 P1 = {0.f,0.f,0.f,0.f}, Q1 = {0.f,0.f,0.f,0.f};
    #pragma unroll
    for (int s = 0; s < 7; ++s){
      const unsigned short* ap = &tile[yl*strd[s] + ofs[s] + pr*8];
      bf16x8 a0 = *reinterpret_cast<const bf16x8*>(ap);
      bf16x8 a1 = *reinterpret_cast<const bf16x8*>(ap + 128);
      P0 = __builtin_amdgcn_mfma_f32_16x16x32_bf16(a0, bH[s], P0, 0, 0, 0);
      Q0 = __builtin_amdgcn_mfma_f32_16x16x32_bf16(a0, bL[s], Q0, 0, 0, 0);
      P1 = __builtin_amdgcn_mfma_f32_16x16x32_bf16(a1, bH[s], P1, 0, 0, 0);
      Q1 = __builtin_amdgcn_mfma_f32_16x16x32_bf16(a1, bL[s], Q1, 0, 0, 0);
    }
    EPI(P0, Q0, x0 + tg*4);
    EPI(P1, Q1, x0 + 16 + tg*4);
  }
#undef EPI

  sAcc += __shfl_xor(sAcc, 16); sAcc += __shfl_xor(sAcc, 32);
  qAcc += __shfl_xor(qAcc, 16); qAcc += __shfl_xor(qAcc, 32);
  if (lane < 16){
    int b0 = (pr < 8) ? pr : (8 + pr);
    atomicAdd(&gacc[n*32 + b0],     sAcc);
    atomicAdd(&gacc[n*32 + b0 + 8], qAcc);
  }
}

// ---------------- Kernel T: channel gates + softmaxes -> a1,a2 -----------------
__global__ void kT(const float* __restrict__ gacc, const float* __restrict__ cgw,
                   float* __restrict__ a1a2){
  int n = blockIdx.x*blockDim.x + threadIdx.x;
  if (n >= NN) return;
  const float* g = gacc + n*32;
  float m1[CG], q1[CG], m2[CG], q2[CG];
  #pragma unroll
  for (int c = 0; c < CG; ++c){
    m1[c] = g[c]      * (1.0f/HWSZ);
    q1[c] = g[8+c]    * (1.0f/HWSZ);
    m2[c] = g[16+c]   * (1.0f/HWSZ);
    q2[c] = g[24+c]   * (1.0f/HWSZ);
  }
  float chg1[CG], chg2[CG];
  #pragma unroll
  for (int o = 0; o < CG; ++o){
    float s1 = 0.f, s2 = 0.f;
    #pragma unroll
    for (int i = 0; i < CG; ++i){ s1 = fmaf(cgw[o*CG+i], m1[i], s1); s2 = fmaf(cgw[o*CG+i], m2[i], s2); }
    chg1[o] = sigmoidf_(s1); chg2[o] = sigmoidf_(s2);
  }
  float z1[CG], z2[CG];
  float mx1 = -1e30f, mx2 = -1e30f;
  #pragma unroll
  for (int c = 0; c < CG; ++c){
    z1[c] = chg1[c]*q1[c]; z2[c] = chg2[c]*q2[c];
    mx1 = fmaxf(mx1, z1[c]); mx2 = fmaxf(mx2, z2[c]);
  }
  float su1 = 0.f, su2 = 0.f;
  #pragma unroll
  for (int c = 0; c < CG; ++c){
    z1[c] = __expf(z1[c]-mx1); su1 += z1[c];
    z2[c] = __expf(z2[c]-mx2); su2 += z2[c];
  }
  float i1 = 1.0f/su1, i2 = 1.0f/su2;
  #pragma unroll
  for (int c = 0; c < CG; ++c){
    float x11 = z1[c]*i1;
    float x21 = z2[c]*i2;
    a1a2[n*16 + c]     = x21 * chg1[c];
    a1a2[n*16 + 8 + c] = x11 * chg2[c];
  }
}

// ---------------- Kernel F: final weights + output (4 px/thread) ---------------
__global__ __launch_bounds__(256) void kF(const float* __restrict__ gx,
                                          const unsigned short* __restrict__ x1m,
                                          const unsigned short* __restrict__ x2m,
                                          const float* __restrict__ a1a2,
                                          const float* __restrict__ spw,
                                          float* __restrict__ out){
  int tid = threadIdx.x;
  int bb = blockIdx.x;            // grid NN*16
  int n  = bb >> 4;
  int hw = ((bb & 15) << 10) + tid*4;
  size_t base = (size_t)(n*CG)*HWSZ + hw;
  float a1[CG], a2[CG], sp[CG];
  #pragma unroll
  for (int c = 0; c < CG; ++c){
    a1[c] = a1a2[n*16 + c];
    a2[c] = a1a2[n*16 + 8 + c];
    sp[c] = spw[c];
  }
  float d1[4]  = {0.f,0.f,0.f,0.f}, dd1[4] = {0.f,0.f,0.f,0.f};
  float d2[4]  = {0.f,0.f,0.f,0.f}, dd2[4] = {0.f,0.f,0.f,0.f};
  #pragma unroll
  for (int c = 0; c < CG; ++c){
    ushort4 u1 = *reinterpret_cast<const ushort4*>(x1m + base + (size_t)c*HWSZ);
    ushort4 u2 = *reinterpret_cast<const ushort4*>(x2m + base + (size_t)c*HWSZ);
    #pragma unroll
    for (int p = 0; p < 4; ++p){
      float v1 = bf2f(((const unsigned short*)&u1)[p]);
      float v2 = bf2f(((const unsigned short*)&u2)[p]);
      d1[p]  = fmaf(sp[c], v1, d1[p]);  dd1[p] = fmaf(a1[c], v1, dd1[p]);
      d2[p]  = fmaf(sp[c], v2, d2[p]);  dd2[p] = fmaf(a2[c], v2, dd2[p]);
    }
  }
  float sW[4];
  #pragma unroll
  for (int p = 0; p < 4; ++p){
    float Wv = sigmoidf_(d1[p])*dd1[p] + sigmoidf_(d2[p])*dd2[p];
    sW[p] = sigmoidf_(Wv);
  }
  #pragma unroll
  for (int c = 0; c < CG; ++c){
    float4 g = *reinterpret_cast<const float4*>(gx + base + (size_t)c*HWSZ);
    float4 o;
    o.x = g.x*sW[0]; o.y = g.y*sW[1]; o.z = g.z*sW[2]; o.w = g.w*sW[3];
    *reinterpret_cast<float4*>(out + base + (size_t)c*HWSZ) = o;
  }
}

extern "C" void kernel_launch(void* const* d_in, const int* in_sizes, int n_in,
                              void* d_out, int out_size, void* d_ws, size_t ws_size,
                              hipStream_t stream){
  const float* x   = (const float*)d_in[0];
  const float* afw = (const float*)d_in[1];
  const float* gnw = (const float*)d_in[2];
  const float* gnb = (const float*)d_in[3];
  const float* w1  = (const float*)d_in[4];
  const float* w3  = (const float*)d_in[5];
  const float* w5  = (const float*)d_in[6];
  const float* scw = (const float*)d_in[7];
  const float* cgw = (const float*)d_in[8];
  const float* spw = (const float*)d_in[9];

  char* ws = (char*)d_ws;
  float* sig_h = (float*)(ws + 0);                          // 1 MiB
  float* sig_w = (float*)(ws + 1048576);                    // 1 MiB
  unsigned short* BHg  = (unsigned short*)(ws + 2097152);   // 14336 B (16 KiB slot)
  float* a1a2 = (float*)(ws + 2097152);                     // 16 KiB, aliases BHg (BHg dead before kT)
  unsigned short* BLog = (unsigned short*)(ws + 2113536);   // 4480 B (8 KiB slot)
  unsigned short* x1m = (unsigned short*)(ws + 2121728);             // 64 MiB
  unsigned short* x2m = (unsigned short*)(ws + 2121728 + 67108864);  // 64 MiB

  float* out = (float*)d_out;
  // scratch in d_out (all dead before kF writes out):
  float* xh_ws = (float*)d_out;                             // 1 MiB
  float* xw_ws = (float*)d_out + 262144;                    // 1 MiB
  float* sighA = (float*)((char*)d_out + 2097152);          // 1 MiB
  float* Bgn   = (float*)((char*)d_out + 3145728);          // 8 KiB
  float* gacc  = (float*)((char*)d_out + 3153920);          // 32 KiB
  unsigned short* xbf = (unsigned short*)((char*)d_out + 4194304); // 64 MiB (ends ~68 MiB < 128 MiB)

  kWB<<<24, 256, 0, stream>>>(w1, w3, w5, scw, spw, BHg, BLog, gacc);
  kA1<<<NN*CG, 256, 0, stream>>>(x, xh_ws, xw_ws);
  kA2<<<NN, 256, 0, stream>>>(xh_ws, xw_ws, afw, sig_h, sig_w);
  kB <<<NN, 256, 0, stream>>>(x, sig_h, sig_w, gnw, gnb, Bgn, sighA, xbf);
  kC <<<NN*16, 256, 0, stream>>>(xbf, w1, scw, spw, sig_w, sighA, Bgn, BHg, BLog, x1m, x2m, gacc);
  kT <<<4, 64, 0, stream>>>(gacc, cgw, a1a2);
  kF <<<NN*16, 256, 0, stream>>>(x, x1m, x2m, a1a2, spw, out);
}

// Round 7
// 441.187 us; speedup vs baseline: 1.0186x; 1.0186x over previous
//
#include <hip/hip_runtime.h>
#include <math.h>

#define HH 128
#define WW 128
#define CG 8
#define NN 256
#define HWSZ (HH*WW)
#define GB (36*36*8)   // gated-tile base offset (ushort units)

typedef __bf16 bf16x8 __attribute__((ext_vector_type(8)));
typedef short short8v __attribute__((ext_vector_type(8)));
typedef float f32x4 __attribute__((ext_vector_type(4)));

__device__ __forceinline__ float sigmoidf_(float x){ return 1.0f/(1.0f+__expf(-x)); }

__device__ __forceinline__ unsigned short f2bf(float x){
  __bf16 h = (__bf16)x;
  return __builtin_bit_cast(unsigned short, h);
}
__device__ __forceinline__ float bf2f(unsigned short h){
  union { unsigned u; float f; } v; v.u = ((unsigned)h) << 16; return v.f;
}

// x1-path weight (w5*sw2 + folded sw1*w3, tap25 = sw0*w1 — Agn folded into tile)
__device__ __forceinline__ float wx1_(const float* w1, const float* w3, const float* w5,
                                      float sw0, float sw1, float sw2,
                                      int oc, int ic, int tap){
  if (tap < 25){
    int ky = tap/5, kx = tap - ky*5;
    float wv = sw2 * w5[oc*200 + ic*25 + tap];
    if (ky >= 1 && ky <= 3 && kx >= 1 && kx <= 3)
      wv = fmaf(sw1, w3[oc*72 + ic*9 + (ky-1)*3 + (kx-1)], wv);
    return wv;
  }
  if (tap == 25) return sw0 * w1[oc*CG + ic];
  return 0.f;
}
__device__ __forceinline__ float wx2_(const float* w3, int oc, int ic, int tap){
  if (tap < 25){
    int ky = tap/5, kx = tap - ky*5;
    if (ky >= 1 && ky <= 3 && kx >= 1 && kx <= 3)
      return w3[oc*72 + ic*9 + (ky-1)*3 + (kx-1)];
  }
  return 0.f;
}

// ---------------- Kernel WB: precompute n-independent B tensors + zero gacc ----
__global__ void kWB(const float* __restrict__ w1, const float* __restrict__ w3,
                    const float* __restrict__ w5, const float* __restrict__ scw,
                    const float* __restrict__ spw,
                    unsigned short* __restrict__ BH, unsigned short* __restrict__ BL,
                    float* __restrict__ gacc){
  if (blockIdx.x == 23){
    for (int i = threadIdx.x; i < NN*32; i += 256) gacc[i] = 0.f;
    return;
  }
  int e = blockIdx.x*256 + threadIdx.x;
  float a = scw[0], b = scw[1], c = scw[2];
  float m = fmaxf(a, fmaxf(b, c));
  float e0 = __expf(a-m), e1 = __expf(b-m), e2 = __expf(c-m);
  float inv = 1.0f/(e0+e1+e2);
  float sw0 = e0*inv, sw1 = e1*inv, sw2 = e2*inv;
  if (e < 3584){
    int s = e >> 9, rem = e & 511, nn = rem >> 5, kk = rem & 31;
    int tap = s*4 + (kk >> 3), ic = kk & 7;
    float wv = (nn < 8) ? wx1_(w1,w3,w5,sw0,sw1,sw2,nn,ic,tap)
                        : wx2_(w3,nn-8,ic,tap);
    BH[e] = f2bf(wv);
  } else if (e < 5824){
    int e2 = e - 3584;
    int s = e2 / 320, rem = e2 - s*320, nn = rem >> 5, kk = rem & 31;
    int tap = s*4 + (kk >> 3), ic = kk & 7;
    float outv;
    if (nn < 8){
      float wv = wx1_(w1,w3,w5,sw0,sw1,sw2,nn,ic,tap);
      outv = wv - bf2f(f2bf(wv));
    } else {
      float sum = 0.f;
      #pragma unroll
      for (int oc = 0; oc < CG; ++oc){
        float wv = (nn == 8) ? wx1_(w1,w3,w5,sw0,sw1,sw2,oc,ic,tap)
                             : wx2_(w3,oc,ic,tap);
        sum = fmaf(spw[oc], wv, sum);
      }
      outv = sum;
    }
    BL[e2] = f2bf(outv);
  }
}

// ---------------- Kernel A1: per-(n,c) row & column means (one float4 pass) ----
// Thread owns 4 fixed columns (w0=(tid&31)*4); rows it*8+(tid>>5). Row sums via
// 5-step shfl_xor butterfly within each 32-lane half; col sums in registers then
// one LDS combine. 16 vector loads/thread, single HBM pass, fully coalesced.
__global__ __launch_bounds__(256) void kA1(const float* __restrict__ gx,
                                           float* __restrict__ xh_ws,
                                           float* __restrict__ xw_ws){
  int b = blockIdx.x; int n = b >> 3; int c = b & 7;
  int tid = threadIdx.x;
  __shared__ float rowsum[HH];
  __shared__ float colpart[8][WW];
  const float* img = gx + (size_t)(n*CG+c)*HWSZ;
  int g = tid >> 5, w0 = (tid & 31)*4;
  float4 colacc = make_float4(0.f, 0.f, 0.f, 0.f);
  #pragma unroll
  for (int it = 0; it < 16; ++it){
    float4 v = *reinterpret_cast<const float4*>(img + it*1024 + tid*4);
    colacc.x += v.x; colacc.y += v.y; colacc.z += v.z; colacc.w += v.w;
    float rp = (v.x + v.y) + (v.z + v.w);
    rp += __shfl_xor(rp, 1);  rp += __shfl_xor(rp, 2);  rp += __shfl_xor(rp, 4);
    rp += __shfl_xor(rp, 8);  rp += __shfl_xor(rp, 16);
    if ((tid & 31) == 0) rowsum[it*8 + g] = rp;
  }
  *reinterpret_cast<float4*>(&colpart[g][w0]) = colacc;
  __syncthreads();
  if (tid < WW){
    float s = 0.f;
    #pragma unroll
    for (int gg = 0; gg < 8; ++gg) s += colpart[gg][tid];
    xw_ws[(n*CG+c)*WW + tid] = s * (1.0f/HH);
  } else {
    int h = tid - 128;
    xh_ws[(n*CG+c)*HH + h] = rowsum[h] * (1.0f/WW);
  }
}

// ---------------- Kernel A2: 8x8 fuse conv + sigmoid ---------------------------
__global__ __launch_bounds__(256) void kA2(const float* __restrict__ xh_ws,
                                           const float* __restrict__ xw_ws,
                                           const float* __restrict__ afw,
                                           float* __restrict__ sig_h,
                                           float* __restrict__ sig_w){
  int n = blockIdx.x;
  int tid = threadIdx.x;
  if (tid < HH){
    int h = tid;
    float v[CG];
    #pragma unroll
    for (int c = 0; c < CG; ++c) v[c] = xh_ws[(n*CG+c)*HH + h];
    #pragma unroll
    for (int o = 0; o < CG; ++o){
      float s = 0.f;
      #pragma unroll
      for (int i = 0; i < CG; ++i) s = fmaf(afw[o*CG+i], v[i], s);
      sig_h[(n*CG+o)*HH + h] = sigmoidf_(s);
    }
  } else {
    int w = tid - 128;
    float v[CG];
    #pragma unroll
    for (int c = 0; c < CG; ++c) v[c] = xw_ws[(n*CG+c)*WW + w];
    #pragma unroll
    for (int o = 0; o < CG; ++o){
      float s = 0.f;
      #pragma unroll
      for (int i = 0; i < CG; ++i) s = fmaf(afw[o*CG+i], v[i], s);
      sig_w[(n*CG+o)*WW + w] = sigmoidf_(s);
    }
  }
}

// ---------------- Kernel B: GroupNorm stats; writes Bgn + sighA = sigh*Agn -----
// float4 reads (same column-owner layout as kA1); sigw hoisted to registers.
__global__ __launch_bounds__(256) void kB(const float* __restrict__ gx,
                                          const float* __restrict__ sig_h,
                                          const float* __restrict__ sig_w,
                                          const float* __restrict__ gn_w,
                                          const float* __restrict__ gn_b,
                                          float* __restrict__ Bgn,
                                          float* __restrict__ sighA){
  int b = blockIdx.x; int n = b >> 3; int c = b & 7;
  int tid = threadIdx.x;
  __shared__ float sh[HH];
  __shared__ float swv[WW];
  __shared__ float red[16];
  __shared__ float sAb;
  if (tid < HH) sh[tid] = sig_h[(n*CG+c)*HH + tid];
  else          swv[tid-128] = sig_w[(n*CG+c)*WW + tid - 128];
  __syncthreads();
  const float* img = gx + (size_t)(n*CG+c)*HWSZ;
  int g = tid >> 5, w0 = (tid & 31)*4;
  float q0 = swv[w0], q1 = swv[w0+1], q2 = swv[w0+2], q3 = swv[w0+3];
  float s1 = 0.f, s2 = 0.f;
  #pragma unroll
  for (int it = 0; it < 16; ++it){
    float4 v = *reinterpret_cast<const float4*>(img + it*1024 + tid*4);
    float shh = sh[it*8 + g];
    float t0 = v.x*shh*q0, t1 = v.y*shh*q1, t2 = v.z*shh*q2, t3 = v.w*shh*q3;
    s1 += (t0+t1) + (t2+t3);
    s2 = fmaf(t0,t0,s2); s2 = fmaf(t1,t1,s2); s2 = fmaf(t2,t2,s2); s2 = fmaf(t3,t3,s2);
  }
  #pragma unroll
  for (int off = 32; off; off >>= 1){ s1 += __shfl_down(s1, off); s2 += __shfl_down(s2, off); }
  int wv = tid >> 6, ln = tid & 63;
  if (ln == 0){ red[wv] = s1; red[8+wv] = s2; }
  __syncthreads();
  if (tid == 0){
    float S1 = red[0]+red[1]+red[2]+red[3];
    float S2 = red[8]+red[9]+red[10]+red[11];
    float mu  = S1 * (1.0f/HWSZ);
    float var = S2 * (1.0f/HWSZ) - mu*mu;
    float rstd = rsqrtf(var + 1e-5f);
    float A = rstd * gn_w[c];
    Bgn[n*CG+c] = gn_b[c] - mu*A;
    sAb = A;
  }
  __syncthreads();
  if (tid < HH) sighA[(n*CG+c)*HH + tid] = sh[tid] * sAb;
}

// ---------------- Kernel C: MFMA implicit-GEMM fused convs ---------------------
// B tensors precomputed (kWB), loaded per-lane from global (L2-hot).
// Agn folded into the gated tile (A-side). Fused staging writes raw halo tile
// (stride 36) + gated 32x32 tile (stride 32, base GB) in one pass.
// Pair-processing: each iteration computes both 16-pixel half-rows of a row,
// reusing B fragments (kept in VGPRs; never in LDS).
__global__ __launch_bounds__(256) void kC(const float* __restrict__ gx,
                                          const float* __restrict__ w1,
                                          const float* __restrict__ scale_w,
                                          const float* __restrict__ spw,
                                          const float* __restrict__ sig_w,
                                          const float* __restrict__ sighA,
                                          const float* __restrict__ Bgn,
                                          const unsigned short* __restrict__ BHg,
                                          const unsigned short* __restrict__ BLog,
                                          unsigned short* __restrict__ x1m,
                                          unsigned short* __restrict__ x2m,
                                          float* __restrict__ gacc){
  __shared__ __align__(16) unsigned short tile[36*36*8 + 32*32*8]; // 37120 B
  __shared__ float shf[CG*32];     // sigh*Agn, f32
  __shared__ float swf[CG*32];     // sigw, f32
  __shared__ float constA[CG];

  int tid = threadIdx.x;
  int bb = blockIdx.x;
  int n  = bb >> 4;
  int t_ = bb & 15;
  int y0 = (t_ >> 2) * 32;
  int x0 = (t_ & 3) * 32;

  int lane = tid & 63, wid = tid >> 6;
  int pr = lane & 15, tg = lane >> 4;

  // B fragments from global (coalesced, L2-resident)
  bf16x8 bH[7], bL[7];
  #pragma unroll
  for (int s = 0; s < 7; ++s)
    bH[s] = *reinterpret_cast<const bf16x8*>(BHg + s*512 + pr*32 + tg*8);
  short8v zs = {0,0,0,0,0,0,0,0};
  bf16x8 zb = __builtin_bit_cast(bf16x8, zs);
  if (pr < 10){
    #pragma unroll
    for (int s = 0; s < 7; ++s)
      bL[s] = *reinterpret_cast<const bf16x8*>(BLog + s*320 + pr*32 + tg*8);
  } else {
    #pragma unroll
    for (int s = 0; s < 7; ++s) bL[s] = zb;
  }

  float sw0;
  {
    float a = scale_w[0], b = scale_w[1], c = scale_w[2];
    float m = fmaxf(a, fmaxf(b, c));
    float e0 = __expf(a-m), e1 = __expf(b-m), e2 = __expf(c-m);
    sw0 = e0 / (e0+e1+e2);
  }
  {
    int ic = tid >> 5, k = tid & 31;
    shf[ic*32+k] = sighA[(n*CG+ic)*HH + y0 + k];
    swf[ic*32+k] = sig_w[(n*CG+ic)*WW + x0 + k];
  }
  if (tid < CG){
    float s = 0.f;
    #pragma unroll
    for (int i = 0; i < CG; ++i) s = fmaf(w1[tid*CG+i], Bgn[n*CG+i], s);
    constA[tid] = sw0 * s;
  }
  __syncthreads();

  // fused staging: raw 36x36 halo tile + gated 32x32 center tile
  const float* base_n = gx + (size_t)n*CG*HWSZ;
  for (int e = tid; e < 1296; e += 256){
    int yy = e / 36, xx = e - yy*36;
    int gy = y0 + yy - 2, gz = x0 + xx - 2;
    float v[8];
    uint4 pk; unsigned* pw = (unsigned*)&pk;
    if ((unsigned)gy < HH && (unsigned)gz < WW){
      int o = gy*WW + gz;
      #pragma unroll
      for (int p = 0; p < 4; ++p){
        v[2*p]   = base_n[(size_t)(2*p)*HWSZ + o];
        v[2*p+1] = base_n[(size_t)(2*p+1)*HWSZ + o];
        pw[p] = (unsigned)f2bf(v[2*p]) | ((unsigned)f2bf(v[2*p+1]) << 16);
      }
    } else {
      #pragma unroll
      for (int p = 0; p < 4; ++p){ v[2*p] = 0.f; v[2*p+1] = 0.f; pw[p] = 0u; }
    }
    *reinterpret_cast<uint4*>(&tile[e*8]) = pk;
    int yl = yy - 2, xl = xx - 2;
    if ((unsigned)yl < 32u && (unsigned)xl < 32u){
      uint4 gk; unsigned* gw = (unsigned*)&gk;
      #pragma unroll
      for (int p = 0; p < 4; ++p){
        float t0 = v[2*p]   * shf[(2*p)*32   + yl] * swf[(2*p)*32   + xl];
        float t1 = v[2*p+1] * shf[(2*p+1)*32 + yl] * swf[(2*p+1)*32 + xl];
        gw[p] = (unsigned)f2bf(t0) | ((unsigned)f2bf(t1) << 16);
      }
      *reinterpret_cast<uint4*>(&tile[GB + (yl*32 + xl)*8]) = gk;
    }
  }

  // per-lane tap geometry (raw: stride 36 rows; gated: stride 32 rows at GB)
  int strd[7], ofs[7];
  #pragma unroll
  for (int s = 0; s < 7; ++s){
    int t = s*4 + tg;
    if (t < 25){ int ky = t/5, kx = t - ky*5; strd[s] = 36*8; ofs[s] = (ky*36 + kx)*8; }
    else if (t == 25){ strd[s] = 32*8; ofs[s] = GB; }
    else { strd[s] = 36*8; ofs[s] = 0; }   // dummy taps (B=0)
  }
  float Cd1 = 0.f;
  #pragma unroll
  for (int oc = 0; oc < CG; ++oc) Cd1 = fmaf(spw[oc], constA[oc], Cd1);
  float cA = (pr < 8) ? constA[pr] : 0.f;
  int gsrc = (lane & 48) | (pr < 8 ? 8 : 9);
  __syncthreads();

  float sAcc = 0.f, qAcc = 0.f;

#define EPI(P, Q, GXX) do { \
    float gq[4]; \
    _Pragma("unroll") \
    for (int r = 0; r < 4; ++r) gq[r] = __shfl(Q[r], gsrc); \
    ushort4 u; \
    _Pragma("unroll") \
    for (int r = 0; r < 4; ++r){ \
      float vvr = (pr < 8) ? (P[r] + Q[r] + cA) : P[r]; \
      float d   = (pr < 8) ? (gq[r] + Cd1) : gq[r]; \
      float sg  = sigmoidf_(d); \
      sAcc += vvr; \
      qAcc = fmaf(vvr, sg, qAcc); \
      ((unsigned short*)&u)[r] = f2bf(vvr); \
    } \
    size_t off = ((size_t)(n*CG + (pr & 7))*HH + (y0 + yl))*WW + (GXX); \
    if (pr < 8) *reinterpret_cast<ushort4*>(x1m + off) = u; \
    else        *reinterpret_cast<ushort4*>(x2m + off) = u; \
  } while(0)

  #pragma unroll 1
  for (int ii = 0; ii < 8; ++ii){
    int yl = wid*8 + ii;
    f32x4 P0 = {0.f,0.f,0.f,0.f}, Q0 = {0.f,0.f,0.f,0.f};
    f32x4 P1 = {0.f,0.f,0.f,0.f}, Q1 = {0.f,0.f,0.f,0.f};
    #pragma unroll
    for (int s = 0; s < 7; ++s){
      const unsigned short* ap = &tile[yl*strd[s] + ofs[s] + pr*8];
      bf16x8 a0 = *reinterpret_cast<const bf16x8*>(ap);
      bf16x8 a1 = *reinterpret_cast<const bf16x8*>(ap + 128);
      P0 = __builtin_amdgcn_mfma_f32_16x16x32_bf16(a0, bH[s], P0, 0, 0, 0);
      Q0 = __builtin_amdgcn_mfma_f32_16x16x32_bf16(a0, bL[s], Q0, 0, 0, 0);
      P1 = __builtin_amdgcn_mfma_f32_16x16x32_bf16(a1, bH[s], P1, 0, 0, 0);
      Q1 = __builtin_amdgcn_mfma_f32_16x16x32_bf16(a1, bL[s], Q1, 0, 0, 0);
    }
    EPI(P0, Q0, x0 + tg*4);
    EPI(P1, Q1, x0 + 16 + tg*4);
  }
#undef EPI

  sAcc += __shfl_xor(sAcc, 16); sAcc += __shfl_xor(sAcc, 32);
  qAcc += __shfl_xor(qAcc, 16); qAcc += __shfl_xor(qAcc, 32);
  if (lane < 16){
    int b0 = (pr < 8) ? pr : (8 + pr);
    atomicAdd(&gacc[n*32 + b0],     sAcc);
    atomicAdd(&gacc[n*32 + b0 + 8], qAcc);
  }
}

// ---------------- Kernel T: channel gates + softmaxes -> a1,a2 -----------------
__global__ void kT(const float* __restrict__ gacc, const float* __restrict__ cgw,
                   float* __restrict__ a1a2){
  int n = blockIdx.x*blockDim.x + threadIdx.x;
  if (n >= NN) return;
  const float* g = gacc + n*32;
  float m1[CG], q1[CG], m2[CG], q2[CG];
  #pragma unroll
  for (int c = 0; c < CG; ++c){
    m1[c] = g[c]      * (1.0f/HWSZ);
    q1[c] = g[8+c]    * (1.0f/HWSZ);
    m2[c] = g[16+c]   * (1.0f/HWSZ);
    q2[c] = g[24+c]   * (1.0f/HWSZ);
  }
  float chg1[CG], chg2[CG];
  #pragma unroll
  for (int o = 0; o < CG; ++o){
    float s1 = 0.f, s2 = 0.f;
    #pragma unroll
    for (int i = 0; i < CG; ++i){ s1 = fmaf(cgw[o*CG+i], m1[i], s1); s2 = fmaf(cgw[o*CG+i], m2[i], s2); }
    chg1[o] = sigmoidf_(s1); chg2[o] = sigmoidf_(s2);
  }
  float z1[CG], z2[CG];
  float mx1 = -1e30f, mx2 = -1e30f;
  #pragma unroll
  for (int c = 0; c < CG; ++c){
    z1[c] = chg1[c]*q1[c]; z2[c] = chg2[c]*q2[c];
    mx1 = fmaxf(mx1, z1[c]); mx2 = fmaxf(mx2, z2[c]);
  }
  float su1 = 0.f, su2 = 0.f;
  #pragma unroll
  for (int c = 0; c < CG; ++c){
    z1[c] = __expf(z1[c]-mx1); su1 += z1[c];
    z2[c] = __expf(z2[c]-mx2); su2 += z2[c];
  }
  float i1 = 1.0f/su1, i2 = 1.0f/su2;
  #pragma unroll
  for (int c = 0; c < CG; ++c){
    float x11 = z1[c]*i1;
    float x21 = z2[c]*i2;
    a1a2[n*16 + c]     = x21 * chg1[c];
    a1a2[n*16 + 8 + c] = x11 * chg2[c];
  }
}

// ---------------- Kernel F: final weights + output (4 px/thread) ---------------
__global__ __launch_bounds__(256) void kF(const float* __restrict__ gx,
                                          const unsigned short* __restrict__ x1m,
                                          const unsigned short* __restrict__ x2m,
                                          const float* __restrict__ a1a2,
                                          const float* __restrict__ spw,
                                          float* __restrict__ out){
  int tid = threadIdx.x;
  int bb = blockIdx.x;            // grid NN*16
  int n  = bb >> 4;
  int hw = ((bb & 15) << 10) + tid*4;
  size_t base = (size_t)(n*CG)*HWSZ + hw;
  float a1[CG], a2[CG], sp[CG];
  #pragma unroll
  for (int c = 0; c < CG; ++c){
    a1[c] = a1a2[n*16 + c];
    a2[c] = a1a2[n*16 + 8 + c];
    sp[c] = spw[c];
  }
  float d1[4]  = {0.f,0.f,0.f,0.f}, dd1[4] = {0.f,0.f,0.f,0.f};
  float d2[4]  = {0.f,0.f,0.f,0.f}, dd2[4] = {0.f,0.f,0.f,0.f};
  #pragma unroll
  for (int c = 0; c < CG; ++c){
    ushort4 u1 = *reinterpret_cast<const ushort4*>(x1m + base + (size_t)c*HWSZ);
    ushort4 u2 = *reinterpret_cast<const ushort4*>(x2m + base + (size_t)c*HWSZ);
    #pragma unroll
    for (int p = 0; p < 4; ++p){
      float v1 = bf2f(((const unsigned short*)&u1)[p]);
      float v2 = bf2f(((const unsigned short*)&u2)[p]);
      d1[p]  = fmaf(sp[c], v1, d1[p]);  dd1[p] = fmaf(a1[c], v1, dd1[p]);
      d2[p]  = fmaf(sp[c], v2, d2[p]);  dd2[p] = fmaf(a2[c], v2, dd2[p]);
    }
  }
  float sW[4];
  #pragma unroll
  for (int p = 0; p < 4; ++p){
    float Wv = sigmoidf_(d1[p])*dd1[p] + sigmoidf_(d2[p])*dd2[p];
    sW[p] = sigmoidf_(Wv);
  }
  #pragma unroll
  for (int c = 0; c < CG; ++c){
    float4 g = *reinterpret_cast<const float4*>(gx + base + (size_t)c*HWSZ);
    float4 o;
    o.x = g.x*sW[0]; o.y = g.y*sW[1]; o.z = g.z*sW[2]; o.w = g.w*sW[3];
    *reinterpret_cast<float4*>(out + base + (size_t)c*HWSZ) = o;
  }
}

extern "C" void kernel_launch(void* const* d_in, const int* in_sizes, int n_in,
                              void* d_out, int out_size, void* d_ws, size_t ws_size,
                              hipStream_t stream){
  const float* x   = (const float*)d_in[0];
  const float* afw = (const float*)d_in[1];
  const float* gnw = (const float*)d_in[2];
  const float* gnb = (const float*)d_in[3];
  const float* w1  = (const float*)d_in[4];
  const float* w3  = (const float*)d_in[5];
  const float* w5  = (const float*)d_in[6];
  const float* scw = (const float*)d_in[7];
  const float* cgw = (const float*)d_in[8];
  const float* spw = (const float*)d_in[9];

  char* ws = (char*)d_ws;
  float* sig_h = (float*)(ws + 0);                          // 1 MiB
  float* sig_w = (float*)(ws + 1048576);                    // 1 MiB
  unsigned short* BHg  = (unsigned short*)(ws + 2097152);   // 14336 B (16 KiB slot)
  float* a1a2 = (float*)(ws + 2097152);                     // 16 KiB, aliases BHg (BHg dead before kT)
  unsigned short* BLog = (unsigned short*)(ws + 2113536);   // 4480 B (8 KiB slot)
  unsigned short* x1m = (unsigned short*)(ws + 2121728);             // 64 MiB
  unsigned short* x2m = (unsigned short*)(ws + 2121728 + 67108864);  // 64 MiB

  float* out = (float*)d_out;
  // scratch in d_out (all dead before kF writes out):
  float* xh_ws = (float*)d_out;                             // 1 MiB
  float* xw_ws = (float*)d_out + 262144;                    // 1 MiB
  float* sighA = (float*)((char*)d_out + 2097152);          // 1 MiB
  float* Bgn   = (float*)((char*)d_out + 3145728);          // 8 KiB
  float* gacc  = (float*)((char*)d_out + 3153920);          // 32 KiB

  kWB<<<24, 256, 0, stream>>>(w1, w3, w5, scw, spw, BHg, BLog, gacc);
  kA1<<<NN*CG, 256, 0, stream>>>(x, xh_ws, xw_ws);
  kA2<<<NN, 256, 0, stream>>>(xh_ws, xw_ws, afw, sig_h, sig_w);
  kB <<<NN*CG, 256, 0, stream>>>(x, sig_h, sig_w, gnw, gnb, Bgn, sighA);
  kC <<<NN*16, 256, 0, stream>>>(x, w1, scw, spw, sig_w, sighA, Bgn, BHg, BLog, x1m, x2m, gacc);
  kT <<<4, 64, 0, stream>>>(gacc, cgw, a1a2);
  kF <<<NN*16, 256, 0, stream>>>(x, x1m, x2m, a1a2, spw, out);
}